// Round 7
// baseline (56109.619 us; speedup 1.0000x reference)
//
#include <hip/hip_runtime.h>
#include <math.h>

// RNNAttentionDecoder on MI355X — round 7: no LDS staging (direct relaxed-atomic
// activation reads, latency pipelined per-lane), 4 barriers/step (att ∥ pred-h1,
// pred acc held in registers across the barrier), coalesced f4 out stores.
// All f32 (argmax feedback forbids bf16; no fp32 MFMA on CDNA4).

typedef unsigned long long u64;

#define NS 196
#define ND 512
#define NK 256
#define NV 10000
#define NT 300
#define NBLK 256
#define NTHR 512
#define SCOPE __HIP_MEMORY_SCOPE_AGENT

__device__ __forceinline__ float sigm(float x) { return 1.0f / (1.0f + expf(-x)); }

__device__ __forceinline__ float aldf(const float* p) {
  return __hip_atomic_load(p, __ATOMIC_RELAXED, SCOPE);
}
__device__ __forceinline__ void astf(float* p, float v) {
  __hip_atomic_store(p, v, __ATOMIC_RELAXED, SCOPE);
}
__device__ __forceinline__ u64 aldu(const u64* p) {
  return __hip_atomic_load(p, __ATOMIC_RELAXED, SCOPE);
}
__device__ __forceinline__ void astu(u64* p, u64 v) {
  __hip_atomic_store(p, v, __ATOMIC_RELAXED, SCOPE);
}

// monotone f32 -> u32, packed with (0xFFFFFFFF - v): max() = (max value, smallest idx)
__device__ __forceinline__ u64 packmax(float x, int v) {
  unsigned u = __float_as_uint(x);
  u = (u & 0x80000000u) ? ~u : (u | 0x80000000u);
  return ((u64)u << 32) | (u64)(0xFFFFFFFFu - (unsigned)v);
}

// ---- fence-free hierarchical grid barrier (round-6 validated) ----
__device__ __forceinline__ void gbar(unsigned* bar, int bid, unsigned ep, bool fenced) {
  __syncthreads();
  if (threadIdx.x == 0) {
    if (fenced) __threadfence();
    asm volatile("s_waitcnt vmcnt(0)" ::: "memory");
    const int g = bid & 7;
    const unsigned old = __hip_atomic_fetch_add(&bar[g * 32], 1u, __ATOMIC_RELAXED, SCOPE);
    if (old == ep * 32u - 1u) {
      const unsigned r = __hip_atomic_fetch_add(&bar[512], 1u, __ATOMIC_RELAXED, SCOPE);
      if (r == ep * 8u - 1u) {
#pragma unroll
        for (int i = 0; i < 8; ++i)
          __hip_atomic_store(&bar[256 + i * 32], ep, __ATOMIC_RELAXED, SCOPE);
      }
    }
    while (__hip_atomic_load(&bar[256 + g * 32], __ATOMIC_RELAXED, SCOPE) < ep)
      __builtin_amdgcn_s_sleep(1);
    if (fenced) __threadfence();
  }
  __syncthreads();
}

__global__ __launch_bounds__(256) void k_zbar(unsigned* bar) {
  const int i = blockIdx.x * 256 + threadIdx.x;
  if (i < 1024) bar[i] = 0u;
}

struct Params {
  const float *x, *emb, *Wk, *bk, *Wv, *bv, *Wq, *bq, *Wp, *bp;
  const float *Wih0, *Whh0, *bih0, *bhh0, *Wih1, *Whh1, *bih1, *bhh1;
  float *out, *keys, *values, *h0t, *h1t, *c0, *c1, *ctx, *wqt;
  u64 *amax;
  unsigned *bar;
};

__global__ __launch_bounds__(NTHR, 1) void k_all(Params p) {
  extern __shared__ float Wp_lds[];   // [40][768] = 30720 floats (120 KB)

  __shared__ int tok_lds[32];
  __shared__ float gp[4][8][32];      // LSTM partials [ks][row][b]
  __shared__ float gsum[8][32];
  __shared__ float pool[5888];        // pred: gpred[4][40][32]; att: hb|qA|eA
  __shared__ u64 cand2[32][10];

  const int bid = blockIdx.x;
  const int t = threadIdx.x;
  const int lane = t & 63;
  const int w = t >> 6;

  // ================= init =================
  {
    const int g = bid * NTHR + t;
    if (g < 65536) astf(&p.h0t[g], 0.0f);            // h0t[2] + h1t[2] contiguous
    if (g < 8192) astf(&p.ctx[g], 0.0f);
    if (g < 256) astu(&p.amax[g], (g < 32) ? ((1ull << 32) | 0xFFFFFFFFull) : 0ull);
    if (g < 131072) {                                 // WqT transpose (one-time)
      const int o = g >> 9, d = g & 511;
      p.wqt[d * 256 + o] = p.Wq[g];
    }
  }
  if (t < 64) {                                       // block-private c0/c1 (plain)
    const int idx = (bid * 2 + (t >> 5)) * 32 + (t & 31);
    p.c0[idx] = 0.0f;
    p.c1[idx] = 0.0f;
  }
  // pin Wp slice in LDS
  if (bid < 250) {
    const float* src = p.Wp + (size_t)bid * 40 * 768;
    for (int i = t; i < 7680; i += NTHR)
      *(float4*)(Wp_lds + 4 * i) = *(const float4*)(src + 4 * i);
  }
  // keys/values (once)
  {
    const int kc = bid & 7, bb = bid >> 3;
    const int kl = t & 31, sg = t >> 5;
    const int k = kc * 32 + kl;
    float ak[13], av[13];
#pragma unroll
    for (int i = 0; i < 13; ++i) { ak[i] = 0.f; av[i] = 0.f; }
    const float* wkr = p.Wk + (size_t)k * ND;
    const float* wvr = p.Wv + (size_t)k * ND;
    const float* xb = p.x + (size_t)bb * NS * ND;
    for (int j = 0; j < ND; j += 4) {
      const float4 wk4 = *(const float4*)(wkr + j);
      const float4 wv4 = *(const float4*)(wvr + j);
#pragma unroll
      for (int si = 0; si < 13; ++si) {
        const int s = sg + si * 16;
        if (s < NS) {
          const float4 xv = *(const float4*)(xb + (size_t)s * ND + j);
          ak[si] += wk4.x * xv.x + wk4.y * xv.y + wk4.z * xv.z + wk4.w * xv.w;
          av[si] += wv4.x * xv.x + wv4.y * xv.y + wv4.z * xv.z + wv4.w * xv.w;
        }
      }
    }
    const float bkk = p.bk[k], bvv = p.bv[k];
#pragma unroll
    for (int si = 0; si < 13; ++si) {
      const int s = sg + si * 16;
      if (s < NS) {
        const size_t o = ((size_t)bb * NS + s) * NK + k;
        p.keys[o] = ak[si] + bkk;
        p.values[o] = av[si] + bvv;
      }
    }
  }
  unsigned ep = 1;
  gbar(p.bar, bid, ep++, true);   // fenced once: flush kv + WqT

  // ================= decode loop =================
  for (int step = 0; step < NT; ++step) {
    const int cur = step & 1;
    const float* h0c = p.h0t + cur * 16384;
    float* h0n = p.h0t + (cur ^ 1) * 16384;
    const float* h1c = p.h1t + cur * 16384;
    float* h1n = p.h1t + (cur ^ 1) * 16384;

    // ===== P1: LSTM0 — direct loads, concat k = [emb 512 | ctx 256 | h0 512] =====
    if (t < 32) {
      u64 m = aldu(&p.amax[t]);
#pragma unroll
      for (int s2 = 1; s2 < 8; ++s2) { const u64 o = aldu(&p.amax[s2 * 32 + t]); if (o > m) m = o; }
      tok_lds[t] = (int)(0xFFFFFFFFu - (unsigned)(m & 0xFFFFFFFFull));
    }
    __syncthreads();
    {
      const int rq = w >> 2, ks = w & 3;
      const int b = lane & 31, kq = lane >> 5;
      const int s8 = ks * 2 + kq;
      int ri[4];
#pragma unroll
      for (int i = 0; i < 4; ++i) {
        const int lr = rq * 4 + i;
        ri[i] = (lr >> 1) * ND + bid * 2 + (lr & 1);
      }
      const float* ebase = p.emb + (size_t)tok_lds[b] * ND;
      float a0 = 0.f, a1 = 0.f, a2 = 0.f, a3 = 0.f;
#pragma unroll 4
      for (int j = 0; j < 40; ++j) {
        const int k0 = s8 * 160 + j * 4;
        float4 x4;
        if (k0 < 512) {
          x4 = *(const float4*)(ebase + k0);
        } else if (k0 < 768) {
          x4.x = aldf(p.ctx + (k0 - 512 + 0) * 32 + b);
          x4.y = aldf(p.ctx + (k0 - 512 + 1) * 32 + b);
          x4.z = aldf(p.ctx + (k0 - 512 + 2) * 32 + b);
          x4.w = aldf(p.ctx + (k0 - 512 + 3) * 32 + b);
        } else {
          x4.x = aldf(h0c + (k0 - 768 + 0) * 32 + b);
          x4.y = aldf(h0c + (k0 - 768 + 1) * 32 + b);
          x4.z = aldf(h0c + (k0 - 768 + 2) * 32 + b);
          x4.w = aldf(h0c + (k0 - 768 + 3) * 32 + b);
        }
        float4 q0, q1, q2, q3;
        if (k0 < 768) {
          q0 = *(const float4*)(p.Wih0 + (size_t)ri[0] * 768 + k0);
          q1 = *(const float4*)(p.Wih0 + (size_t)ri[1] * 768 + k0);
          q2 = *(const float4*)(p.Wih0 + (size_t)ri[2] * 768 + k0);
          q3 = *(const float4*)(p.Wih0 + (size_t)ri[3] * 768 + k0);
        } else {
          q0 = *(const float4*)(p.Whh0 + (size_t)ri[0] * ND + (k0 - 768));
          q1 = *(const float4*)(p.Whh0 + (size_t)ri[1] * ND + (k0 - 768));
          q2 = *(const float4*)(p.Whh0 + (size_t)ri[2] * ND + (k0 - 768));
          q3 = *(const float4*)(p.Whh0 + (size_t)ri[3] * ND + (k0 - 768));
        }
        a0 += q0.x * x4.x + q0.y * x4.y + q0.z * x4.z + q0.w * x4.w;
        a1 += q1.x * x4.x + q1.y * x4.y + q1.z * x4.z + q1.w * x4.w;
        a2 += q2.x * x4.x + q2.y * x4.y + q2.z * x4.z + q2.w * x4.w;
        a3 += q3.x * x4.x + q3.y * x4.y + q3.z * x4.z + q3.w * x4.w;
      }
      a0 += __shfl_xor(a0, 32);
      a1 += __shfl_xor(a1, 32);
      a2 += __shfl_xor(a2, 32);
      a3 += __shfl_xor(a3, 32);
      if (kq == 0) {
        gp[ks][rq * 4 + 0][b] = a0; gp[ks][rq * 4 + 1][b] = a1;
        gp[ks][rq * 4 + 2][b] = a2; gp[ks][rq * 4 + 3][b] = a3;
      }
    }
    __syncthreads();
    if (t < 256) {
      const int r = t >> 5, b2 = t & 31;
      const int grow = (r >> 1) * ND + bid * 2 + (r & 1);
      gsum[r][b2] = gp[0][r][b2] + gp[1][r][b2] + gp[2][r][b2] + gp[3][r][b2]
                  + p.bih0[grow] + p.bhh0[grow];
    }
    __syncthreads();
    if (t < 64) {
      const int dl = t >> 5, b2 = t & 31;
      const int idx = (bid * 2 + dl) * 32 + b2;
      const float gi = gsum[0 + dl][b2], gf = gsum[2 + dl][b2];
      const float gg = gsum[4 + dl][b2], go = gsum[6 + dl][b2];
      const float cn = sigm(gf) * p.c0[idx] + sigm(gi) * tanhf(gg);
      p.c0[idx] = cn;
      astf(&h0n[idx], sigm(go) * tanhf(cn));
    }
    gbar(p.bar, bid, ep++, false);

    // ===== P2: LSTM1 — k = [h0n 512 | h1c 512]; block0 resets amax =====
    if (bid == 0 && t < 256) astu(&p.amax[t], 0ull);
    {
      const int rq = w >> 2, ks = w & 3;
      const int b = lane & 31, kq = lane >> 5;
      const int s8 = ks * 2 + kq;
      int ri[4];
#pragma unroll
      for (int i = 0; i < 4; ++i) {
        const int lr = rq * 4 + i;
        ri[i] = (lr >> 1) * ND + bid * 2 + (lr & 1);
      }
      float a0 = 0.f, a1 = 0.f, a2 = 0.f, a3 = 0.f;
#pragma unroll 4
      for (int j = 0; j < 32; ++j) {
        const int k0 = s8 * 128 + j * 4;
        const float* src = (k0 < 512) ? (h0n + k0 * 32) : (h1c + (k0 - 512) * 32);
        float4 x4;
        x4.x = aldf(src + 0 * 32 + b);
        x4.y = aldf(src + 1 * 32 + b);
        x4.z = aldf(src + 2 * 32 + b);
        x4.w = aldf(src + 3 * 32 + b);
        const float* wbase = (k0 < 512) ? (p.Wih1 + k0) : (p.Whh1 + (k0 - 512));
        const float4 q0 = *(const float4*)(wbase + (size_t)ri[0] * ND);
        const float4 q1 = *(const float4*)(wbase + (size_t)ri[1] * ND);
        const float4 q2 = *(const float4*)(wbase + (size_t)ri[2] * ND);
        const float4 q3 = *(const float4*)(wbase + (size_t)ri[3] * ND);
        a0 += q0.x * x4.x + q0.y * x4.y + q0.z * x4.z + q0.w * x4.w;
        a1 += q1.x * x4.x + q1.y * x4.y + q1.z * x4.z + q1.w * x4.w;
        a2 += q2.x * x4.x + q2.y * x4.y + q2.z * x4.z + q2.w * x4.w;
        a3 += q3.x * x4.x + q3.y * x4.y + q3.z * x4.z + q3.w * x4.w;
      }
      a0 += __shfl_xor(a0, 32);
      a1 += __shfl_xor(a1, 32);
      a2 += __shfl_xor(a2, 32);
      a3 += __shfl_xor(a3, 32);
      if (kq == 0) {
        gp[ks][rq * 4 + 0][b] = a0; gp[ks][rq * 4 + 1][b] = a1;
        gp[ks][rq * 4 + 2][b] = a2; gp[ks][rq * 4 + 3][b] = a3;
      }
    }
    __syncthreads();
    if (t < 256) {
      const int r = t >> 5, b2 = t & 31;
      const int grow = (r >> 1) * ND + bid * 2 + (r & 1);
      gsum[r][b2] = gp[0][r][b2] + gp[1][r][b2] + gp[2][r][b2] + gp[3][r][b2]
                  + p.bih1[grow] + p.bhh1[grow];
    }
    __syncthreads();
    if (t < 64) {
      const int dl = t >> 5, b2 = t & 31;
      const int idx = (bid * 2 + dl) * 32 + b2;
      const float gi = gsum[0 + dl][b2], gf = gsum[2 + dl][b2];
      const float gg = gsum[4 + dl][b2], go = gsum[6 + dl][b2];
      const float cn = sigm(gf) * p.c1[idx] + sigm(gi) * tanhf(gg);
      p.c1[idx] = cn;
      astf(&h1n[idx], sigm(go) * tanhf(cn));
    }
    gbar(p.bar, bid, ep++, false);

    // ===== P3: pred-h1-part (blocks <250) ∥ attention (blocks 250..255) =====
    float acc[20];   // pred accumulators live across the next barrier
#pragma unroll
    for (int r = 0; r < 20; ++r) acc[r] = 0.f;
    if (bid < 250) {
      const int rq = w >> 2, ks = w & 3;
      const int b = lane & 31, kq = lane >> 5;
      const int kbase = ks * 128 + kq * 64;
#pragma unroll 2
      for (int j = 0; j < 16; ++j) {
        const int k0 = kbase + j * 4;
        float4 x4;
        x4.x = aldf(h1n + (k0 + 0) * 32 + b);
        x4.y = aldf(h1n + (k0 + 1) * 32 + b);
        x4.z = aldf(h1n + (k0 + 2) * 32 + b);
        x4.w = aldf(h1n + (k0 + 3) * 32 + b);
#pragma unroll
        for (int r = 0; r < 20; ++r) {
          const float4 w4 = *(const float4*)(Wp_lds + (size_t)(rq * 20 + r) * 768 + k0);
          acc[r] += w4.x * x4.x + w4.y * x4.y + w4.z * x4.z + w4.w * x4.w;
        }
      }
    } else {
      const int ai = bid - 250;
      const int b0 = ai * 6;
      const int nb = (32 - b0 < 6) ? (32 - b0) : 6;
      float* hb = pool;           // [6][512]
      float* qA = pool + 3072;    // [6][256]
      float* eA = pool + 4608;    // [6][200]
      for (int bb = 0; bb < nb; ++bb)
        hb[bb * 512 + t] = aldf(h1n + t * 32 + (b0 + bb));
      __syncthreads();
      {  // q = WqT^T h1 + bq, scaled; thread (o, dh)
        const int o = t & 255, dh = t >> 8;
        float acc6[6];
#pragma unroll
        for (int bb = 0; bb < 6; ++bb) acc6[bb] = 0.f;
        const float* wq = p.wqt + (size_t)dh * 256 * 256 + o;
        const float* hbb = hb + dh * 256;
#pragma unroll 4
        for (int dd = 0; dd < 256; ++dd) {
          const float wv = wq[dd * 256];
#pragma unroll
          for (int bb = 0; bb < 6; ++bb) acc6[bb] += wv * hbb[bb * 512 + dd];
        }
        if (dh == 1) {
          for (int bb = 0; bb < nb; ++bb) qA[bb * 256 + o] = acc6[bb];
        }
        __syncthreads();
        if (dh == 0) {
          const float bqo = p.bq[o];
          for (int bb = 0; bb < nb; ++bb)
            qA[bb * 256 + o] = (acc6[bb] + qA[bb * 256 + o] + bqo) * 0.0625f;
        }
      }
      __syncthreads();
      // energies: wave-dot over 256 (q pre-scaled)
      for (int bb = 0; bb < nb; ++bb) {
        const float* kb = p.keys + ((size_t)(b0 + bb) * NS) * NK + (lane << 2);
        const float4 q4 = *(const float4*)(qA + bb * 256 + (lane << 2));
        for (int s = w; s < NS; s += 8) {
          const float4 k4 = *(const float4*)(kb + (size_t)s * NK);
          float v = k4.x * q4.x + k4.y * q4.y + k4.z * q4.z + k4.w * q4.w;
#pragma unroll
          for (int mk = 1; mk < 64; mk <<= 1) v += __shfl_xor(v, mk);
          if (lane == 0) eA[bb * 200 + s] = v;
        }
      }
      __syncthreads();
      // softmax: one wave per batch (wave-synchronous)
      if (w < nb) {
        float el[4];
#pragma unroll
        for (int i = 0; i < 4; ++i) {
          const int s = lane + 64 * i;
          el[i] = (s < NS) ? eA[w * 200 + s] : -INFINITY;
        }
        float m = fmaxf(fmaxf(el[0], el[1]), fmaxf(el[2], el[3]));
#pragma unroll
        for (int mk = 1; mk < 64; mk <<= 1) m = fmaxf(m, __shfl_xor(m, mk));
        float pe[4], sum = 0.f;
#pragma unroll
        for (int i = 0; i < 4; ++i) { pe[i] = expf(el[i] - m); sum += pe[i]; }
#pragma unroll
        for (int mk = 1; mk < 64; mk <<= 1) sum += __shfl_xor(sum, mk);
        const float inv = 1.0f / sum;
#pragma unroll
        for (int i = 0; i < 4; ++i) {
          const int s = lane + 64 * i;
          if (s < NS) eA[w * 200 + s] = pe[i] * inv;
        }
      }
      __syncthreads();
      // ctx = smx @ values
      for (int u = t; u < nb * 256; u += NTHR) {
        const int bb = u >> 8, k = u & 255;
        const float* vb = p.values + ((size_t)(b0 + bb) * NS) * NK + k;
        const float* sm = eA + bb * 200;
        float a = 0.f;
#pragma unroll 4
        for (int s = 0; s < NS; ++s) a += sm[s] * vb[(size_t)s * NK];
        astf(p.ctx + k * 32 + (b0 + bb), a);
      }
    }
    gbar(p.bar, bid, ep++, false);

    // ===== P4: pred-ctx-part + reduce + argmax + coalesced out =====
    if (bid < 250) {
      const int rq = w >> 2, ks = w & 3;
      const int b = lane & 31, kq = lane >> 5;
      const int kbase = 512 + ks * 64 + kq * 32;
#pragma unroll 2
      for (int j = 0; j < 8; ++j) {
        const int k0 = kbase + j * 4;
        float4 x4;
        x4.x = aldf(p.ctx + (k0 - 512 + 0) * 32 + b);
        x4.y = aldf(p.ctx + (k0 - 512 + 1) * 32 + b);
        x4.z = aldf(p.ctx + (k0 - 512 + 2) * 32 + b);
        x4.w = aldf(p.ctx + (k0 - 512 + 3) * 32 + b);
#pragma unroll
        for (int r = 0; r < 20; ++r) {
          const float4 w4 = *(const float4*)(Wp_lds + (size_t)(rq * 20 + r) * 768 + k0);
          acc[r] += w4.x * x4.x + w4.y * x4.y + w4.z * x4.z + w4.w * x4.w;
        }
      }
#pragma unroll
      for (int r = 0; r < 20; ++r) acc[r] += __shfl_xor(acc[r], 32);
      if (kq == 0) {
#pragma unroll
        for (int r = 0; r < 20; ++r)
          pool[ks * 1280 + (rq * 20 + r) * 32 + b] = acc[r];
      }
      __syncthreads();
      if (t < 320) {
        const int b = t & 31, rg = t >> 5;
        const int vb = bid * 40 + rg * 4;
        float4 v;
        float* vp = &v.x;
#pragma unroll
        for (int i = 0; i < 4; ++i) {
          const int row = rg * 4 + i;
          vp[i] = pool[0 * 1280 + row * 32 + b] + pool[1 * 1280 + row * 32 + b]
                + pool[2 * 1280 + row * 32 + b] + pool[3 * 1280 + row * 32 + b]
                + p.bp[vb + i];
        }
        *(float4*)(p.out + ((size_t)b * NT + step) * NV + vb) = v;
        u64 m = packmax(v.x, vb + 0);
        u64 o1 = packmax(v.y, vb + 1); if (o1 > m) m = o1;
        u64 o2 = packmax(v.z, vb + 2); if (o2 > m) m = o2;
        u64 o3 = packmax(v.w, vb + 3); if (o3 > m) m = o3;
        cand2[b][rg] = m;
      }
      __syncthreads();
      if (t < 32) {
        u64 mm = cand2[t][0];
#pragma unroll
        for (int i = 1; i < 10; ++i) { const u64 o = cand2[t][i]; if (o > mm) mm = o; }
        (void)__hip_atomic_fetch_max(&p.amax[(bid & 7) * 32 + t], mm, __ATOMIC_RELAXED, SCOPE);
      }
    }
    gbar(p.bar, bid, ep++, false);
  }
}

// ---------------- host ----------------
extern "C" void kernel_launch(void* const* d_in, const int* in_sizes, int n_in,
                              void* d_out, int out_size, void* d_ws, size_t ws_size,
                              hipStream_t stream) {
  (void)in_sizes; (void)n_in; (void)out_size; (void)ws_size;
  Params prm;
  prm.x    = (const float*)d_in[0];
  prm.emb  = (const float*)d_in[1];
  prm.Wk   = (const float*)d_in[2];
  prm.bk   = (const float*)d_in[3];
  prm.Wv   = (const float*)d_in[4];
  prm.bv   = (const float*)d_in[5];
  prm.Wq   = (const float*)d_in[6];
  prm.bq   = (const float*)d_in[7];
  prm.Wp   = (const float*)d_in[8];
  prm.bp   = (const float*)d_in[9];
  prm.Wih0 = (const float*)d_in[10];
  prm.Whh0 = (const float*)d_in[11];
  prm.bih0 = (const float*)d_in[12];
  prm.bhh0 = (const float*)d_in[13];
  prm.Wih1 = (const float*)d_in[14];
  prm.Whh1 = (const float*)d_in[15];
  prm.bih1 = (const float*)d_in[16];
  prm.bhh1 = (const float*)d_in[17];
  prm.out  = (float*)d_out;

  float* ws = (float*)d_ws;
  prm.keys   = ws;                          // 1,605,632
  prm.values = prm.keys + 1605632;          // 1,605,632
  prm.h0t    = prm.values + 1605632;        // [2][512][32] = 32,768
  prm.h1t    = prm.h0t + 32768;             // 32,768
  prm.c0     = prm.h1t + 32768;             // 16,384 (block-private)
  prm.c1     = prm.c0 + 16384;              // 16,384 (block-private)
  prm.ctx    = prm.c1 + 16384;              // [256][32] = 8,192
  prm.amax   = (u64*)(prm.ctx + 8192);      // 256 u64 = 512 f
  prm.wqt    = prm.ctx + 8192 + 512;        // [512][256] = 131,072
  prm.bar    = (unsigned*)(prm.wqt + 131072);  // 1,024 u32

  const int LDS = 30720 * 4;                // 122,880 B dynamic (Wp only)
  (void)hipFuncSetAttribute((const void*)k_all, hipFuncAttributeMaxDynamicSharedMemorySize, LDS);

  k_zbar<<<4, 256, 0, stream>>>(prm.bar);
  void* args[] = { &prm };
  (void)hipLaunchCooperativeKernel((const void*)k_all, dim3(NBLK), dim3(NTHR), args,
                                   (unsigned)LDS, stream);
}

// Round 8
// 26781.866 us; speedup vs baseline: 2.0951x; 2.0951x over previous
//
#include <hip/hip_runtime.h>
#include <math.h>

// RNNAttentionDecoder on MI355X — round 8: R6 base (stable fence-free barrier,
// staged coalesced emb, Wp pinned in LDS) + direct b-coalesced activation reads
// (no chunk syncs for ctx/h0/h1/pred) + coalesced f4 out stores (kills the 11x
// write amplification that the barrier's vmcnt(0) drain was paying for).
// All f32 (argmax feedback forbids bf16; no fp32 MFMA on CDNA4).

typedef unsigned long long u64;

#define NS 196
#define ND 512
#define NK 256
#define NV 10000
#define NT 300
#define NBLK 256
#define NTHR 512
#define SCOPE __HIP_MEMORY_SCOPE_AGENT

__device__ __forceinline__ float sigm(float x) { return 1.0f / (1.0f + expf(-x)); }

__device__ __forceinline__ float aldf(const float* p) {
  return __hip_atomic_load(p, __ATOMIC_RELAXED, SCOPE);
}
__device__ __forceinline__ void astf(float* p, float v) {
  __hip_atomic_store(p, v, __ATOMIC_RELAXED, SCOPE);
}
__device__ __forceinline__ u64 aldu(const u64* p) {
  return __hip_atomic_load(p, __ATOMIC_RELAXED, SCOPE);
}
__device__ __forceinline__ void astu(u64* p, u64 v) {
  __hip_atomic_store(p, v, __ATOMIC_RELAXED, SCOPE);
}

// monotone f32 -> u32, packed with (0xFFFFFFFF - v): max() = (max value, smallest idx)
__device__ __forceinline__ u64 packmax(float x, int v) {
  unsigned u = __float_as_uint(x);
  u = (u & 0x80000000u) ? ~u : (u | 0x80000000u);
  return ((u64)u << 32) | (u64)(0xFFFFFFFFu - (unsigned)v);
}

// swizzled f4-slot in the 16KB stage [32 rows][32 f4]
__device__ __forceinline__ int eslot(int b, int k4) {
  return b * 32 + ((k4 & ~7) | ((k4 ^ b) & 7));
}

// ---- fence-free hierarchical grid barrier (round-6 validated) ----
__device__ __forceinline__ void gbar(unsigned* bar, int bid, unsigned ep, bool fenced) {
  __syncthreads();
  if (threadIdx.x == 0) {
    if (fenced) __threadfence();
    asm volatile("s_waitcnt vmcnt(0)" ::: "memory");
    const int g = bid & 7;
    const unsigned old = __hip_atomic_fetch_add(&bar[g * 32], 1u, __ATOMIC_RELAXED, SCOPE);
    if (old == ep * 32u - 1u) {
      const unsigned r = __hip_atomic_fetch_add(&bar[512], 1u, __ATOMIC_RELAXED, SCOPE);
      if (r == ep * 8u - 1u) {
#pragma unroll
        for (int i = 0; i < 8; ++i)
          __hip_atomic_store(&bar[256 + i * 32], ep, __ATOMIC_RELAXED, SCOPE);
      }
    }
    while (__hip_atomic_load(&bar[256 + g * 32], __ATOMIC_RELAXED, SCOPE) < ep)
      __builtin_amdgcn_s_sleep(2);
    if (fenced) __threadfence();
  }
  __syncthreads();
}

__global__ __launch_bounds__(256) void k_zbar(unsigned* bar) {
  const int i = blockIdx.x * 256 + threadIdx.x;
  if (i < 1024) bar[i] = 0u;
}

struct Params {
  const float *x, *emb, *Wk, *bk, *Wv, *bv, *Wq, *bq, *Wp, *bp;
  const float *Wih0, *Whh0, *bih0, *bhh0, *Wih1, *Whh1, *bih1, *bhh1;
  float *out, *keys, *values, *h0t, *h1t, *c0, *c1, *ctx, *qg;
  u64 *amax;
  unsigned *bar;
};

__global__ __launch_bounds__(NTHR, 1) void k_all(Params p) {
  extern __shared__ float dyn[];
  float* Wp_lds = dyn;          // [40][768] = 30720 floats (120 KB)
  float* stage  = dyn + 30720;  // [32][32] f4-slots = 4096 floats (16 KB)

  // shared arena, phase-aliased:
  //  P1/P2: gp = arena[0..1023] ([4][8][32]), gsum = arena[1024..1279]
  //  P3   : gpf = arena[0..2047]
  //  P4   : attq = arena[0..255], red = arena[256..511], smx = arena[512..767]
  //  P5   : pool = arena[0..2559] ([2][40][32])
  __shared__ __align__(16) float arena[2560];
  __shared__ int tok_lds[32];
  __shared__ u64 cand2[32][10];

  const int bid = blockIdx.x;
  const int t = threadIdx.x;
  const int lane = t & 63;
  const int w = t >> 6;

#define GP(ks, r, b)  arena[((ks) * 8 + (r)) * 32 + (b)]
#define GS(r, b)      arena[1024 + (r) * 32 + (b)]

  // ================= init =================
  {
    const int g = bid * NTHR + t;
    if (g < 65536) astf(&p.h0t[g], 0.0f);        // h0t[2] + h1t[2]
    if (g < 8192) astf(&p.ctx[g], 0.0f);
    if (g < 256) astu(&p.amax[g], (g < 32) ? ((1ull << 32) | 0xFFFFFFFFull) : 0ull);
  }
  if (t < 64) {   // block-private c0/c1: plain stores by the owning block
    const int idx = (bid * 2 + (t >> 5)) * 32 + (t & 31);
    p.c0[idx] = 0.0f;
    p.c1[idx] = 0.0f;
  }
  // pin Wp slice in LDS (once)
  if (bid < 250) {
    const float* src = p.Wp + (size_t)bid * 40 * 768;
    for (int i = t; i < 7680; i += NTHR)
      *(float4*)(Wp_lds + 4 * i) = *(const float4*)(src + 4 * i);
  }
  // keys/values (once)
  {
    const int kc = bid & 7, bb = bid >> 3;
    const int kl = t & 31, sg = t >> 5;
    const int k = kc * 32 + kl;
    float ak[13], av[13];
#pragma unroll
    for (int i = 0; i < 13; ++i) { ak[i] = 0.f; av[i] = 0.f; }
    const float* wkr = p.Wk + (size_t)k * ND;
    const float* wvr = p.Wv + (size_t)k * ND;
    const float* xb = p.x + (size_t)bb * NS * ND;
    for (int j = 0; j < ND; j += 4) {
      const float4 wk4 = *(const float4*)(wkr + j);
      const float4 wv4 = *(const float4*)(wvr + j);
#pragma unroll
      for (int si = 0; si < 13; ++si) {
        const int s = sg + si * 16;
        if (s < NS) {
          const float4 xv = *(const float4*)(xb + (size_t)s * ND + j);
          ak[si] += wk4.x * xv.x + wk4.y * xv.y + wk4.z * xv.z + wk4.w * xv.w;
          av[si] += wv4.x * xv.x + wv4.y * xv.y + wv4.z * xv.z + wv4.w * xv.w;
        }
      }
    }
    const float bkk = p.bk[k], bvv = p.bv[k];
#pragma unroll
    for (int si = 0; si < 13; ++si) {
      const int s = sg + si * 16;
      if (s < NS) {
        const size_t o = ((size_t)bb * NS + s) * NK + k;
        p.keys[o] = ak[si] + bkk;
        p.values[o] = av[si] + bvv;
      }
    }
  }
  unsigned ep = 1;
  gbar(p.bar, bid, ep++, true);   // fenced once: flush kv

  // ================= decode loop =================
  for (int step = 0; step < NT; ++step) {
    const int cur = step & 1;
    const float* h0c = p.h0t + cur * 16384;
    float* h0n = p.h0t + (cur ^ 1) * 16384;
    const float* h1c = p.h1t + cur * 16384;
    float* h1n = p.h1t + (cur ^ 1) * 16384;

    // ===== P1: LSTM0 — emb staged (coalesced), ctx/h0 direct b-coalesced =====
    if (t < 32) {
      u64 m = aldu(&p.amax[t]);
#pragma unroll
      for (int s2 = 1; s2 < 8; ++s2) { const u64 o = aldu(&p.amax[s2 * 32 + t]); if (o > m) m = o; }
      tok_lds[t] = (int)(0xFFFFFFFFu - (unsigned)(m & 0xFFFFFFFFull));
    }
    __syncthreads();
    {
      const int rq = w >> 2, ks = w & 3;
      const int b = lane & 31, kq = lane >> 5;
      const int s8 = ks * 2 + kq;
      const int rb = rq * 4;
      int rg4[4];
#pragma unroll
      for (int i = 0; i < 4; ++i) rg4[i] = ((rb + i) >> 1) * ND + bid * 2 + ((rb + i) & 1);
      float a0 = 0.f, a1 = 0.f, a2 = 0.f, a3 = 0.f;
      // emb part: 4 staged chunks of [32 rows][32 f4]
      for (int c = 0; c < 4; ++c) {
        {
          const int eb = t >> 4, sl = t & 15;
          const float* er = p.emb + (size_t)tok_lds[eb] * ND + c * 128;
          *(float4*)(stage + 4 * eslot(eb, sl)) = *(const float4*)(er + 4 * sl);
          *(float4*)(stage + 4 * eslot(eb, sl + 16)) = *(const float4*)(er + 4 * (sl + 16));
        }
        __syncthreads();
#pragma unroll
        for (int jj = 0; jj < 4; ++jj) {
          const int f4 = ks * 8 + kq * 4 + jj;
          const float4 a4 = *(const float4*)(stage + 4 * eslot(b, f4));
          const int wc = c * 128 + 4 * f4;
          const float4 q0 = *(const float4*)(p.Wih0 + (size_t)rg4[0] * 768 + wc);
          const float4 q1 = *(const float4*)(p.Wih0 + (size_t)rg4[1] * 768 + wc);
          const float4 q2 = *(const float4*)(p.Wih0 + (size_t)rg4[2] * 768 + wc);
          const float4 q3 = *(const float4*)(p.Wih0 + (size_t)rg4[3] * 768 + wc);
          a0 += q0.x * a4.x + q0.y * a4.y + q0.z * a4.z + q0.w * a4.w;
          a1 += q1.x * a4.x + q1.y * a4.y + q1.z * a4.z + q1.w * a4.w;
          a2 += q2.x * a4.x + q2.y * a4.y + q2.z * a4.z + q2.w * a4.w;
          a3 += q3.x * a4.x + q3.y * a4.y + q3.z * a4.z + q3.w * a4.w;
        }
        __syncthreads();
      }
      // ctx part (k 512..767): direct, coalesced over b
#pragma unroll 4
      for (int j = 0; j < 8; ++j) {
        const int k0 = (s8 * 8 + j) * 4;
        float4 x4;
        x4.x = aldf(p.ctx + (k0 + 0) * 32 + b);
        x4.y = aldf(p.ctx + (k0 + 1) * 32 + b);
        x4.z = aldf(p.ctx + (k0 + 2) * 32 + b);
        x4.w = aldf(p.ctx + (k0 + 3) * 32 + b);
        const int wc = 512 + k0;
        const float4 q0 = *(const float4*)(p.Wih0 + (size_t)rg4[0] * 768 + wc);
        const float4 q1 = *(const float4*)(p.Wih0 + (size_t)rg4[1] * 768 + wc);
        const float4 q2 = *(const float4*)(p.Wih0 + (size_t)rg4[2] * 768 + wc);
        const float4 q3 = *(const float4*)(p.Wih0 + (size_t)rg4[3] * 768 + wc);
        a0 += q0.x * x4.x + q0.y * x4.y + q0.z * x4.z + q0.w * x4.w;
        a1 += q1.x * x4.x + q1.y * x4.y + q1.z * x4.z + q1.w * x4.w;
        a2 += q2.x * x4.x + q2.y * x4.y + q2.z * x4.z + q2.w * x4.w;
        a3 += q3.x * x4.x + q3.y * x4.y + q3.z * x4.z + q3.w * x4.w;
      }
      // h0 part (512): direct, coalesced over b
#pragma unroll 4
      for (int j = 0; j < 16; ++j) {
        const int k0 = (s8 * 16 + j) * 4;
        float4 x4;
        x4.x = aldf(h0c + (k0 + 0) * 32 + b);
        x4.y = aldf(h0c + (k0 + 1) * 32 + b);
        x4.z = aldf(h0c + (k0 + 2) * 32 + b);
        x4.w = aldf(h0c + (k0 + 3) * 32 + b);
        const float4 q0 = *(const float4*)(p.Whh0 + (size_t)rg4[0] * ND + k0);
        const float4 q1 = *(const float4*)(p.Whh0 + (size_t)rg4[1] * ND + k0);
        const float4 q2 = *(const float4*)(p.Whh0 + (size_t)rg4[2] * ND + k0);
        const float4 q3 = *(const float4*)(p.Whh0 + (size_t)rg4[3] * ND + k0);
        a0 += q0.x * x4.x + q0.y * x4.y + q0.z * x4.z + q0.w * x4.w;
        a1 += q1.x * x4.x + q1.y * x4.y + q1.z * x4.z + q1.w * x4.w;
        a2 += q2.x * x4.x + q2.y * x4.y + q2.z * x4.z + q2.w * x4.w;
        a3 += q3.x * x4.x + q3.y * x4.y + q3.z * x4.z + q3.w * x4.w;
      }
      a0 += __shfl_xor(a0, 32);
      a1 += __shfl_xor(a1, 32);
      a2 += __shfl_xor(a2, 32);
      a3 += __shfl_xor(a3, 32);
      if (kq == 0) {
        GP(ks, rb + 0, b) = a0; GP(ks, rb + 1, b) = a1;
        GP(ks, rb + 2, b) = a2; GP(ks, rb + 3, b) = a3;
      }
    }
    __syncthreads();
    if (t < 256) {
      const int r = t >> 5, b2 = t & 31;
      const int grow = (r >> 1) * ND + bid * 2 + (r & 1);
      GS(r, b2) = GP(0, r, b2) + GP(1, r, b2) + GP(2, r, b2) + GP(3, r, b2)
                + p.bih0[grow] + p.bhh0[grow];
    }
    __syncthreads();
    if (t < 64) {
      const int dl = t >> 5, b2 = t & 31;
      const int idx = (bid * 2 + dl) * 32 + b2;
      const float gi = GS(0 + dl, b2), gf = GS(2 + dl, b2);
      const float gg = GS(4 + dl, b2), go = GS(6 + dl, b2);
      const float cn = sigm(gf) * p.c0[idx] + sigm(gi) * tanhf(gg);
      p.c0[idx] = cn;
      astf(&h0n[idx], sigm(go) * tanhf(cn));
    }
    gbar(p.bar, bid, ep++, false);

    // ===== P2: LSTM1 — direct reads; block0 resets amax =====
    if (bid == 0 && t < 256) astu(&p.amax[t], 0ull);
    {
      const int rq = w >> 2, ks = w & 3;
      const int b = lane & 31, kq = lane >> 5;
      const int s8 = ks * 2 + kq;
      int rg4[4];
#pragma unroll
      for (int i = 0; i < 4; ++i) {
        const int lr = rq * 4 + i;
        rg4[i] = (lr >> 1) * ND + bid * 2 + (lr & 1);
      }
      float a0 = 0.f, a1 = 0.f, a2 = 0.f, a3 = 0.f;
#pragma unroll 4
      for (int j = 0; j < 32; ++j) {
        const int k0 = s8 * 128 + j * 4;
        const float* src = (k0 < 512) ? (h0n + k0 * 32) : (h1c + (k0 - 512) * 32);
        float4 x4;
        x4.x = aldf(src + 0 * 32 + b);
        x4.y = aldf(src + 1 * 32 + b);
        x4.z = aldf(src + 2 * 32 + b);
        x4.w = aldf(src + 3 * 32 + b);
        const float* wbase = (k0 < 512) ? (p.Wih1 + k0) : (p.Whh1 + (k0 - 512));
        const float4 q0 = *(const float4*)(wbase + (size_t)rg4[0] * ND);
        const float4 q1 = *(const float4*)(wbase + (size_t)rg4[1] * ND);
        const float4 q2 = *(const float4*)(wbase + (size_t)rg4[2] * ND);
        const float4 q3 = *(const float4*)(wbase + (size_t)rg4[3] * ND);
        a0 += q0.x * x4.x + q0.y * x4.y + q0.z * x4.z + q0.w * x4.w;
        a1 += q1.x * x4.x + q1.y * x4.y + q1.z * x4.z + q1.w * x4.w;
        a2 += q2.x * x4.x + q2.y * x4.y + q2.z * x4.z + q2.w * x4.w;
        a3 += q3.x * x4.x + q3.y * x4.y + q3.z * x4.z + q3.w * x4.w;
      }
      a0 += __shfl_xor(a0, 32);
      a1 += __shfl_xor(a1, 32);
      a2 += __shfl_xor(a2, 32);
      a3 += __shfl_xor(a3, 32);
      if (kq == 0) {
        GP(ks, rq * 4 + 0, b) = a0; GP(ks, rq * 4 + 1, b) = a1;
        GP(ks, rq * 4 + 2, b) = a2; GP(ks, rq * 4 + 3, b) = a3;
      }
    }
    __syncthreads();
    if (t < 256) {
      const int r = t >> 5, b2 = t & 31;
      const int grow = (r >> 1) * ND + bid * 2 + (r & 1);
      GS(r, b2) = GP(0, r, b2) + GP(1, r, b2) + GP(2, r, b2) + GP(3, r, b2)
                + p.bih1[grow] + p.bhh1[grow];
    }
    __syncthreads();
    if (t < 64) {
      const int dl = t >> 5, b2 = t & 31;
      const int idx = (bid * 2 + dl) * 32 + b2;
      const float gi = GS(0 + dl, b2), gf = GS(2 + dl, b2);
      const float gg = GS(4 + dl, b2), go = GS(6 + dl, b2);
      const float cn = sigm(gf) * p.c1[idx] + sigm(gi) * tanhf(gg);
      p.c1[idx] = cn;
      astf(&h1n[idx], sigm(go) * tanhf(cn));
    }
    gbar(p.bar, bid, ep++, false);

    // ===== P3: Q projection (64 blocks x 4 rows) =====
    if (bid < 64) {
      const int sl = t >> 5, b = t & 31;
      float acc0 = 0.f, acc1 = 0.f, acc2 = 0.f, acc3 = 0.f;
      const float* wq0 = p.Wq + (size_t)(bid * 4 + 0) * ND + sl * 32;
      const float* wq1 = p.Wq + (size_t)(bid * 4 + 1) * ND + sl * 32;
      const float* wq2 = p.Wq + (size_t)(bid * 4 + 2) * ND + sl * 32;
      const float* wq3 = p.Wq + (size_t)(bid * 4 + 3) * ND + sl * 32;
#pragma unroll 8
      for (int kk = 0; kk < 32; ++kk) {
        const float hv = aldf(h1n + (sl * 32 + kk) * 32 + b);
        acc0 += wq0[kk] * hv; acc1 += wq1[kk] * hv;
        acc2 += wq2[kk] * hv; acc3 += wq3[kk] * hv;
      }
      arena[(sl * 4 + 0) * 32 + b] = acc0;
      arena[(sl * 4 + 1) * 32 + b] = acc1;
      arena[(sl * 4 + 2) * 32 + b] = acc2;
      arena[(sl * 4 + 3) * 32 + b] = acc3;
      __syncthreads();
      if (t < 128) {
        const int rl = t >> 5, b2 = t & 31;
        float q = 0.f;
#pragma unroll
        for (int s2 = 0; s2 < 16; ++s2) q += arena[(s2 * 4 + rl) * 32 + b2];
        const int r = bid * 4 + rl;
        astf(&p.qg[r * 32 + b2], (q + p.bq[r]) * 0.0625f);  // 1/sqrt(256)
      }
    }
    gbar(p.bar, bid, ep++, false);

    // ===== P4: attention (blocks 0..31, block = batch b) =====
    if (bid < 32) {
      const int b = bid;
      float* attq = arena;
      float* red = arena + 256;
      float* smx = arena + 512;
      if (t < 256) attq[t] = aldf(&p.qg[t * 32 + b]);
      __syncthreads();
      const int kl = lane & 31, rh = lane >> 5;
      for (int pp = 0; pp < 13; ++pp) {
        const int s = pp * 16 + w * 2 + rh;
        float a = 0.f;
        if (s < NS) {
          const float* kr = p.keys + ((size_t)b * NS + s) * NK + kl * 4;
#pragma unroll
          for (int i = 0; i < 2; ++i) {
            const float4 k4 = *(const float4*)(kr + i * 128);
            const float4 q4 = *(const float4*)(attq + i * 128 + kl * 4);
            a += k4.x * q4.x + k4.y * q4.y + k4.z * q4.z + k4.w * q4.w;
          }
        }
#pragma unroll
        for (int mk = 1; mk < 32; mk <<= 1) a += __shfl_xor(a, mk);
        if (kl == 0 && s < NS) smx[s] = a;
      }
      __syncthreads();
      float e = -INFINITY;
      if (t < 256) { e = (t < NS) ? smx[t] : -INFINITY; red[t] = e; }
      __syncthreads();
      for (int off = 128; off; off >>= 1) {
        if (t < off) red[t] = fmaxf(red[t], red[t + off]);
        __syncthreads();
      }
      const float mx = red[0];
      __syncthreads();
      float a = 0.f;
      if (t < 256) { a = (t < NS) ? expf(e - mx) : 0.f; red[t] = a; }
      __syncthreads();
      for (int off = 128; off; off >>= 1) {
        if (t < off) red[t] += red[t + off];
        __syncthreads();
      }
      const float inv = 1.0f / red[0];
      if (t < 256) smx[t] = a * inv;
      __syncthreads();
      if (t < 256) {
        const float* vb = p.values + (size_t)b * NS * NK + t;
        float c0_ = 0.f, c1_ = 0.f, c2_ = 0.f, c3_ = 0.f;
        for (int s = 0; s < NS; s += 4) {
          c0_ += smx[s + 0] * vb[(size_t)(s + 0) * NK];
          c1_ += smx[s + 1] * vb[(size_t)(s + 1) * NK];
          c2_ += smx[s + 2] * vb[(size_t)(s + 2) * NK];
          c3_ += smx[s + 3] * vb[(size_t)(s + 3) * NK];
        }
        astf(&p.ctx[t * 32 + b], (c0_ + c1_) + (c2_ + c3_));
      }
    }
    gbar(p.bar, bid, ep++, false);

    // ===== P5: pred GEMV (fused h1+ctx), coalesced out + argmax =====
    if (bid < 250) {
      const int rgrp = w >> 1, ks2 = w & 1;       // 4 row-groups x 2 k-halves
      const int b = lane & 31, kq = lane >> 5;
      const int s4 = ks2 * 2 + kq;                // 4 k-slices of 48 f4
      float acc[10];
#pragma unroll
      for (int r = 0; r < 10; ++r) acc[r] = 0.f;
#pragma unroll 2
      for (int j = 0; j < 48; ++j) {
        const int k0 = (s4 * 48 + j) * 4;
        const float* src = (k0 < 512) ? (h1n + k0 * 32) : (p.ctx + (k0 - 512) * 32);
        float4 x4;
        x4.x = aldf(src + 0 * 32 + b);
        x4.y = aldf(src + 1 * 32 + b);
        x4.z = aldf(src + 2 * 32 + b);
        x4.w = aldf(src + 3 * 32 + b);
#pragma unroll
        for (int r = 0; r < 10; ++r) {
          const float4 w4 = *(const float4*)(Wp_lds + (size_t)(rgrp * 10 + r) * 768 + k0);
          acc[r] += w4.x * x4.x + w4.y * x4.y + w4.z * x4.z + w4.w * x4.w;
        }
      }
#pragma unroll
      for (int r = 0; r < 10; ++r) acc[r] += __shfl_xor(acc[r], 32);
      if (kq == 0) {
#pragma unroll
        for (int r = 0; r < 10; ++r)
          arena[ks2 * 1280 + (rgrp * 10 + r) * 32 + b] = acc[r];
      }
      __syncthreads();
      if (t < 320) {
        const int b2 = t & 31, rg = t >> 5;       // 10 row-groups of 4
        const int vb = bid * 40 + rg * 4;
        float4 v;
        float* vp = &v.x;
#pragma unroll
        for (int i = 0; i < 4; ++i) {
          const int row = rg * 4 + i;
          vp[i] = arena[row * 32 + b2] + arena[1280 + row * 32 + b2] + p.bp[vb + i];
        }
        *(float4*)(p.out + ((size_t)b2 * NT + step) * NV + vb) = v;
        u64 m = packmax(v.x, vb + 0);
        u64 o1 = packmax(v.y, vb + 1); if (o1 > m) m = o1;
        u64 o2 = packmax(v.z, vb + 2); if (o2 > m) m = o2;
        u64 o3 = packmax(v.w, vb + 3); if (o3 > m) m = o3;
        cand2[b2][rg] = m;
      }
      __syncthreads();
      if (t < 32) {
        u64 mm = cand2[t][0];
#pragma unroll
        for (int i = 1; i < 10; ++i) { const u64 o = cand2[t][i]; if (o > mm) mm = o; }
        (void)__hip_atomic_fetch_max(&p.amax[(bid & 7) * 32 + t], mm, __ATOMIC_RELAXED, SCOPE);
      }
    }
    gbar(p.bar, bid, ep++, false);
  }
#undef GP
#undef GS
}

// ---------------- host ----------------
extern "C" void kernel_launch(void* const* d_in, const int* in_sizes, int n_in,
                              void* d_out, int out_size, void* d_ws, size_t ws_size,
                              hipStream_t stream) {
  (void)in_sizes; (void)n_in; (void)out_size; (void)ws_size;
  Params prm;
  prm.x    = (const float*)d_in[0];
  prm.emb  = (const float*)d_in[1];
  prm.Wk   = (const float*)d_in[2];
  prm.bk   = (const float*)d_in[3];
  prm.Wv   = (const float*)d_in[4];
  prm.bv   = (const float*)d_in[5];
  prm.Wq   = (const float*)d_in[6];
  prm.bq   = (const float*)d_in[7];
  prm.Wp   = (const float*)d_in[8];
  prm.bp   = (const float*)d_in[9];
  prm.Wih0 = (const float*)d_in[10];
  prm.Whh0 = (const float*)d_in[11];
  prm.bih0 = (const float*)d_in[12];
  prm.bhh0 = (const float*)d_in[13];
  prm.Wih1 = (const float*)d_in[14];
  prm.Whh1 = (const float*)d_in[15];
  prm.bih1 = (const float*)d_in[16];
  prm.bhh1 = (const float*)d_in[17];
  prm.out  = (float*)d_out;

  float* ws = (float*)d_ws;
  prm.keys   = ws;                          // 1,605,632
  prm.values = prm.keys + 1605632;          // 1,605,632
  prm.h0t    = prm.values + 1605632;        // [2][512][32] = 32,768
  prm.h1t    = prm.h0t + 32768;             // 32,768
  prm.c0     = prm.h1t + 32768;             // 16,384 (block-private)
  prm.c1     = prm.c0 + 16384;              // 16,384 (block-private)
  prm.ctx    = prm.c1 + 16384;              // [256][32] = 8,192
  prm.amax   = (u64*)(prm.ctx + 8192);      // 256 u64 = 512 f
  prm.qg     = prm.ctx + 8192 + 512;        // [256][32] = 8,192
  prm.bar    = (unsigned*)(prm.qg + 8192);  // 1,024 u32

  const int LDS = (30720 + 4096) * 4;       // 139,264 B dynamic
  (void)hipFuncSetAttribute((const void*)k_all, hipFuncAttributeMaxDynamicSharedMemorySize, LDS);

  k_zbar<<<4, 256, 0, stream>>>(prm.bar);
  void* args[] = { &prm };
  (void)hipLaunchCooperativeKernel((const void*)k_all, dim3(NBLK), dim3(NTHR), args,
                                   (unsigned)LDS, stream);
}

// Round 9
// 24837.387 us; speedup vs baseline: 2.2591x; 1.0783x over previous
//
#include <hip/hip_runtime.h>
#include <math.h>

// RNNAttentionDecoder on MI355X — round 9: LSTM weights pinned in LDS (72 KB,
// zero-latency on the serial critical path), Wp streamed (bandwidth, overlapped),
// 4 barriers/step: LSTM0 | LSTM1 | att(+own q) ∥ pred-h1 | pred-ctx+argmax.
// Fence-free relaxed-atomic coherence (validated R6/R8).
// All f32 (argmax feedback forbids bf16; no fp32 MFMA on CDNA4).

typedef unsigned long long u64;

#define NS 196
#define ND 512
#define NK 256
#define NV 10000
#define NT 300
#define NBLK 256
#define NTHR 512
#define NPRED 209     // pred blocks, 48 rows each (209*48 = 10032 >= 10000)
#define ATT0 224      // att blocks 224..255, one per batch
#define SCOPE __HIP_MEMORY_SCOPE_AGENT

__device__ __forceinline__ float sigm(float x) { return 1.0f / (1.0f + expf(-x)); }

__device__ __forceinline__ float aldf(const float* p) {
  return __hip_atomic_load(p, __ATOMIC_RELAXED, SCOPE);
}
__device__ __forceinline__ void astf(float* p, float v) {
  __hip_atomic_store(p, v, __ATOMIC_RELAXED, SCOPE);
}
__device__ __forceinline__ u64 aldu(const u64* p) {
  return __hip_atomic_load(p, __ATOMIC_RELAXED, SCOPE);
}
__device__ __forceinline__ void astu(u64* p, u64 v) {
  __hip_atomic_store(p, v, __ATOMIC_RELAXED, SCOPE);
}

// monotone f32 -> u32, packed with (0xFFFFFFFF - v): max() = (max value, smallest idx)
__device__ __forceinline__ u64 packmax(float x, int v) {
  unsigned u = __float_as_uint(x);
  u = (u & 0x80000000u) ? ~u : (u | 0x80000000u);
  return ((u64)u << 32) | (u64)(0xFFFFFFFFu - (unsigned)v);
}

// swizzled f4-slot in the 16KB stage [32 rows][32 f4]
__device__ __forceinline__ int eslot(int b, int k4) {
  return b * 32 + ((k4 & ~7) | ((k4 ^ b) & 7));
}

// ---- fence-free hierarchical grid barrier (R6-validated) ----
__device__ __forceinline__ void gbar(unsigned* bar, int bid, unsigned ep, bool fenced) {
  __syncthreads();
  if (threadIdx.x == 0) {
    if (fenced) __threadfence();
    asm volatile("s_waitcnt vmcnt(0)" ::: "memory");
    const int g = bid & 7;
    const unsigned old = __hip_atomic_fetch_add(&bar[g * 32], 1u, __ATOMIC_RELAXED, SCOPE);
    if (old == ep * 32u - 1u) {
      const unsigned r = __hip_atomic_fetch_add(&bar[512], 1u, __ATOMIC_RELAXED, SCOPE);
      if (r == ep * 8u - 1u) {
#pragma unroll
        for (int i = 0; i < 8; ++i)
          __hip_atomic_store(&bar[256 + i * 32], ep, __ATOMIC_RELAXED, SCOPE);
      }
    }
    while (__hip_atomic_load(&bar[256 + g * 32], __ATOMIC_RELAXED, SCOPE) < ep)
      __builtin_amdgcn_s_sleep(1);
    if (fenced) __threadfence();
  }
  __syncthreads();
}

__global__ __launch_bounds__(256) void k_zbar(unsigned* bar) {
  const int i = blockIdx.x * 256 + threadIdx.x;
  if (i < 1024) bar[i] = 0u;
}

struct Params {
  const float *x, *emb, *Wk, *bk, *Wv, *bv, *Wq, *bq, *Wp, *bp;
  const float *Wih0, *Whh0, *bih0, *bhh0, *Wih1, *Whh1, *bih1, *bhh1;
  float *out, *keys, *values, *h0t, *h1t, *c0, *c1, *ctx;
  u64 *amax;
  unsigned *bar;
};

__global__ __launch_bounds__(NTHR, 1) void k_all(Params p) {
  extern __shared__ float dyn[];
  float* W0lds = dyn;                  // [8][1280] = 10240 f (40 KB): Wih0|Whh0 rows
  float* W1lds = dyn + 10240;          // [8][1024] = 8192 f (32 KB): Wih1|Whh1 rows
  float* stage = dyn + 18432;          // [32][32] f4-slots = 4096 f (16 KB)

  // arena aliased per phase:
  //  P1/P2: gp [4][8][32] (0..1023), gsum [8][32] (1024..1279)
  //  P3att: hb (0..511), q (512..767), red (768..1023), smx (1024..1279)
  //  P4   : pred partials [48][32] (0..1535)
  __shared__ __align__(16) float arena[2560];
  __shared__ int tok_lds[32];
  __shared__ u64 cand2[32][12];

  const int bid = blockIdx.x;
  const int t = threadIdx.x;
  const int lane = t & 63;
  const int w = t >> 6;

#define GP(ks, r, b)  arena[((ks) * 8 + (r)) * 32 + (b)]
#define GS(r, b)      arena[1024 + (r) * 32 + (b)]

  // ================= init =================
  {
    const int g = bid * NTHR + t;
    if (g < 65536) astf(&p.h0t[g], 0.0f);        // h0t[2] + h1t[2]
    if (g < 8192) astf(&p.ctx[g], 0.0f);
    if (g < 256) astu(&p.amax[g], (g < 32) ? ((1ull << 32) | 0xFFFFFFFFull) : 0ull);
  }
  if (t < 64) {   // block-private c0/c1
    const int idx = (bid * 2 + (t >> 5)) * 32 + (t & 31);
    p.c0[idx] = 0.0f;
    p.c1[idx] = 0.0f;
  }
  // ---- pin this block's 8 LSTM gate-rows in LDS (once) ----
  {
    const int r = t >> 6, ln = t & 63;
    const int grow = (r >> 1) * ND + bid * 2 + (r & 1);
    const float* s0i = p.Wih0 + (size_t)grow * 768;
    const float* s0h = p.Whh0 + (size_t)grow * ND;
#pragma unroll
    for (int j = 0; j < 5; ++j) {
      const int col = 4 * (ln + 64 * j);           // 0..1276
      const float4 v = (col < 768) ? *(const float4*)(s0i + col)
                                   : *(const float4*)(s0h + (col - 768));
      *(float4*)(W0lds + r * 1280 + col) = v;
    }
    const float* s1i = p.Wih1 + (size_t)grow * ND;
    const float* s1h = p.Whh1 + (size_t)grow * ND;
#pragma unroll
    for (int j = 0; j < 4; ++j) {
      const int col = 4 * (ln + 64 * j);           // 0..1020
      const float4 v = (col < 512) ? *(const float4*)(s1i + col)
                                   : *(const float4*)(s1h + (col - 512));
      *(float4*)(W1lds + r * 1024 + col) = v;
    }
  }
  // ---- keys/values (once) ----
  {
    const int kc = bid & 7, bb = bid >> 3;
    const int kl = t & 31, sg = t >> 5;
    const int k = kc * 32 + kl;
    float ak[13], av[13];
#pragma unroll
    for (int i = 0; i < 13; ++i) { ak[i] = 0.f; av[i] = 0.f; }
    const float* wkr = p.Wk + (size_t)k * ND;
    const float* wvr = p.Wv + (size_t)k * ND;
    const float* xb = p.x + (size_t)bb * NS * ND;
    for (int j = 0; j < ND; j += 4) {
      const float4 wk4 = *(const float4*)(wkr + j);
      const float4 wv4 = *(const float4*)(wvr + j);
#pragma unroll
      for (int si = 0; si < 13; ++si) {
        const int s = sg + si * 16;
        if (s < NS) {
          const float4 xv = *(const float4*)(xb + (size_t)s * ND + j);
          ak[si] += wk4.x * xv.x + wk4.y * xv.y + wk4.z * xv.z + wk4.w * xv.w;
          av[si] += wv4.x * xv.x + wv4.y * xv.y + wv4.z * xv.z + wv4.w * xv.w;
        }
      }
    }
    const float bkk = p.bk[k], bvv = p.bv[k];
#pragma unroll
    for (int si = 0; si < 13; ++si) {
      const int s = sg + si * 16;
      if (s < NS) {
        const size_t o = ((size_t)bb * NS + s) * NK + k;
        p.keys[o] = ak[si] + bkk;
        p.values[o] = av[si] + bvv;
      }
    }
  }
  unsigned ep = 1;
  gbar(p.bar, bid, ep++, true);   // fenced once: flush kv

  // ================= decode loop =================
  for (int step = 0; step < NT; ++step) {
    const int cur = step & 1;
    const float* h0c = p.h0t + cur * 16384;
    float* h0n = p.h0t + (cur ^ 1) * 16384;
    const float* h1c = p.h1t + cur * 16384;
    float* h1n = p.h1t + (cur ^ 1) * 16384;

    // ===== P1: LSTM0 — weights from LDS; emb staged; ctx/h0 direct =====
    if (t < 32) {
      u64 m = aldu(&p.amax[t]);
#pragma unroll
      for (int s2 = 1; s2 < 8; ++s2) { const u64 o = aldu(&p.amax[s2 * 32 + t]); if (o > m) m = o; }
      tok_lds[t] = (int)(0xFFFFFFFFu - (unsigned)(m & 0xFFFFFFFFull));
    }
    __syncthreads();
    {
      const int rq = w >> 2, ks = w & 3;
      const int b = lane & 31, kq = lane >> 5;
      const int s8 = ks * 2 + kq;
      const int rb = rq * 4;
      float a0 = 0.f, a1 = 0.f, a2 = 0.f, a3 = 0.f;
      // emb part: 4 staged chunks of [32 rows][32 f4]
      for (int c = 0; c < 4; ++c) {
        {
          const int eb = t >> 4, sl = t & 15;
          const float* er = p.emb + (size_t)tok_lds[eb] * ND + c * 128;
          *(float4*)(stage + 4 * eslot(eb, sl)) = *(const float4*)(er + 4 * sl);
          *(float4*)(stage + 4 * eslot(eb, sl + 16)) = *(const float4*)(er + 4 * (sl + 16));
        }
        __syncthreads();
#pragma unroll
        for (int jj = 0; jj < 4; ++jj) {
          const int f4 = ks * 8 + kq * 4 + jj;
          const float4 a4 = *(const float4*)(stage + 4 * eslot(b, f4));
          const int wc = c * 128 + 4 * f4;
          const float4 q0 = *(const float4*)(W0lds + (rb + 0) * 1280 + wc);
          const float4 q1 = *(const float4*)(W0lds + (rb + 1) * 1280 + wc);
          const float4 q2 = *(const float4*)(W0lds + (rb + 2) * 1280 + wc);
          const float4 q3 = *(const float4*)(W0lds + (rb + 3) * 1280 + wc);
          a0 += q0.x * a4.x + q0.y * a4.y + q0.z * a4.z + q0.w * a4.w;
          a1 += q1.x * a4.x + q1.y * a4.y + q1.z * a4.z + q1.w * a4.w;
          a2 += q2.x * a4.x + q2.y * a4.y + q2.z * a4.z + q2.w * a4.w;
          a3 += q3.x * a4.x + q3.y * a4.y + q3.z * a4.z + q3.w * a4.w;
        }
        __syncthreads();
      }
      // ctx part (cols 512..767): direct, coalesced over b
#pragma unroll 4
      for (int j = 0; j < 8; ++j) {
        const int k0 = (s8 * 8 + j) * 4;
        float4 x4;
        x4.x = aldf(p.ctx + (k0 + 0) * 32 + b);
        x4.y = aldf(p.ctx + (k0 + 1) * 32 + b);
        x4.z = aldf(p.ctx + (k0 + 2) * 32 + b);
        x4.w = aldf(p.ctx + (k0 + 3) * 32 + b);
        const int wc = 512 + k0;
        const float4 q0 = *(const float4*)(W0lds + (rb + 0) * 1280 + wc);
        const float4 q1 = *(const float4*)(W0lds + (rb + 1) * 1280 + wc);
        const float4 q2 = *(const float4*)(W0lds + (rb + 2) * 1280 + wc);
        const float4 q3 = *(const float4*)(W0lds + (rb + 3) * 1280 + wc);
        a0 += q0.x * x4.x + q0.y * x4.y + q0.z * x4.z + q0.w * x4.w;
        a1 += q1.x * x4.x + q1.y * x4.y + q1.z * x4.z + q1.w * x4.w;
        a2 += q2.x * x4.x + q2.y * x4.y + q2.z * x4.z + q2.w * x4.w;
        a3 += q3.x * x4.x + q3.y * x4.y + q3.z * x4.z + q3.w * x4.w;
      }
      // h0 part (cols 768..1279): direct, coalesced over b
#pragma unroll 4
      for (int j = 0; j < 16; ++j) {
        const int k0 = (s8 * 16 + j) * 4;
        float4 x4;
        x4.x = aldf(h0c + (k0 + 0) * 32 + b);
        x4.y = aldf(h0c + (k0 + 1) * 32 + b);
        x4.z = aldf(h0c + (k0 + 2) * 32 + b);
        x4.w = aldf(h0c + (k0 + 3) * 32 + b);
        const int wc = 768 + k0;
        const float4 q0 = *(const float4*)(W0lds + (rb + 0) * 1280 + wc);
        const float4 q1 = *(const float4*)(W0lds + (rb + 1) * 1280 + wc);
        const float4 q2 = *(const float4*)(W0lds + (rb + 2) * 1280 + wc);
        const float4 q3 = *(const float4*)(W0lds + (rb + 3) * 1280 + wc);
        a0 += q0.x * x4.x + q0.y * x4.y + q0.z * x4.z + q0.w * x4.w;
        a1 += q1.x * x4.x + q1.y * x4.y + q1.z * x4.z + q1.w * x4.w;
        a2 += q2.x * x4.x + q2.y * x4.y + q2.z * x4.z + q2.w * x4.w;
        a3 += q3.x * x4.x + q3.y * x4.y + q3.z * x4.z + q3.w * x4.w;
      }
      a0 += __shfl_xor(a0, 32);
      a1 += __shfl_xor(a1, 32);
      a2 += __shfl_xor(a2, 32);
      a3 += __shfl_xor(a3, 32);
      if (kq == 0) {
        GP(ks, rb + 0, b) = a0; GP(ks, rb + 1, b) = a1;
        GP(ks, rb + 2, b) = a2; GP(ks, rb + 3, b) = a3;
      }
    }
    __syncthreads();
    if (t < 256) {
      const int r = t >> 5, b2 = t & 31;
      const int grow = (r >> 1) * ND + bid * 2 + (r & 1);
      GS(r, b2) = GP(0, r, b2) + GP(1, r, b2) + GP(2, r, b2) + GP(3, r, b2)
                + p.bih0[grow] + p.bhh0[grow];
    }
    __syncthreads();
    if (t < 64) {
      const int dl = t >> 5, b2 = t & 31;
      const int idx = (bid * 2 + dl) * 32 + b2;
      const float gi = GS(0 + dl, b2), gf = GS(2 + dl, b2);
      const float gg = GS(4 + dl, b2), go = GS(6 + dl, b2);
      const float cn = sigm(gf) * p.c0[idx] + sigm(gi) * tanhf(gg);
      p.c0[idx] = cn;
      astf(&h0n[idx], sigm(go) * tanhf(cn));
    }
    gbar(p.bar, bid, ep++, false);

    // ===== P2: LSTM1 — weights from LDS; block0 resets amax =====
    if (bid == 0 && t < 256) astu(&p.amax[t], 0ull);
    {
      const int rq = w >> 2, ks = w & 3;
      const int b = lane & 31, kq = lane >> 5;
      const int s8 = ks * 2 + kq;
      const int rb = rq * 4;
      float a0 = 0.f, a1 = 0.f, a2 = 0.f, a3 = 0.f;
#pragma unroll 4
      for (int j = 0; j < 32; ++j) {
        const int k0 = s8 * 128 + j * 4;
        const float* src = (k0 < 512) ? (h0n + k0 * 32) : (h1c + (k0 - 512) * 32);
        float4 x4;
        x4.x = aldf(src + 0 * 32 + b);
        x4.y = aldf(src + 1 * 32 + b);
        x4.z = aldf(src + 2 * 32 + b);
        x4.w = aldf(src + 3 * 32 + b);
        const float4 q0 = *(const float4*)(W1lds + (rb + 0) * 1024 + k0);
        const float4 q1 = *(const float4*)(W1lds + (rb + 1) * 1024 + k0);
        const float4 q2 = *(const float4*)(W1lds + (rb + 2) * 1024 + k0);
        const float4 q3 = *(const float4*)(W1lds + (rb + 3) * 1024 + k0);
        a0 += q0.x * x4.x + q0.y * x4.y + q0.z * x4.z + q0.w * x4.w;
        a1 += q1.x * x4.x + q1.y * x4.y + q1.z * x4.z + q1.w * x4.w;
        a2 += q2.x * x4.x + q2.y * x4.y + q2.z * x4.z + q2.w * x4.w;
        a3 += q3.x * x4.x + q3.y * x4.y + q3.z * x4.z + q3.w * x4.w;
      }
      a0 += __shfl_xor(a0, 32);
      a1 += __shfl_xor(a1, 32);
      a2 += __shfl_xor(a2, 32);
      a3 += __shfl_xor(a3, 32);
      if (kq == 0) {
        GP(ks, rb + 0, b) = a0; GP(ks, rb + 1, b) = a1;
        GP(ks, rb + 2, b) = a2; GP(ks, rb + 3, b) = a3;
      }
    }
    __syncthreads();
    if (t < 256) {
      const int r = t >> 5, b2 = t & 31;
      const int grow = (r >> 1) * ND + bid * 2 + (r & 1);
      GS(r, b2) = GP(0, r, b2) + GP(1, r, b2) + GP(2, r, b2) + GP(3, r, b2)
                + p.bih1[grow] + p.bhh1[grow];
    }
    __syncthreads();
    if (t < 64) {
      const int dl = t >> 5, b2 = t & 31;
      const int idx = (bid * 2 + dl) * 32 + b2;
      const float gi = GS(0 + dl, b2), gf = GS(2 + dl, b2);
      const float gg = GS(4 + dl, b2), go = GS(6 + dl, b2);
      const float cn = sigm(gf) * p.c1[idx] + sigm(gi) * tanhf(gg);
      p.c1[idx] = cn;
      astf(&h1n[idx], sigm(go) * tanhf(cn));
    }
    gbar(p.bar, bid, ep++, false);

    // ===== P3: attention (blocks 224..255, own q) ∥ pred-h1 (blocks 0..208) =====
    float acc[6];   // pred accumulators live across the next barrier
#pragma unroll
    for (int r = 0; r < 6; ++r) acc[r] = 0.f;
    if (bid >= ATT0) {
      const int b = bid - ATT0;
      float* hb  = arena;          // [512]
      float* qs  = arena + 512;    // [256]
      float* red = arena + 768;    // [256]
      float* smx = arena + 1024;   // [256]
      hb[t] = aldf(h1n + t * 32 + b);
      __syncthreads();
      const int kl = lane & 31, rh = lane >> 5;
      // q = Wq @ h1_b + bq, scaled: 8 waves x 32 rows
      for (int pp = 0; pp < 16; ++pp) {
        const int r = w * 32 + pp * 2 + rh;
        const float* wq = p.Wq + (size_t)r * ND + kl * 4;
        float a = 0.f;
#pragma unroll
        for (int i = 0; i < 4; ++i) {
          const float4 w4 = *(const float4*)(wq + i * 128);
          const float4 h4 = *(const float4*)(hb + i * 128 + kl * 4);
          a += w4.x * h4.x + w4.y * h4.y + w4.z * h4.z + w4.w * h4.w;
        }
#pragma unroll
        for (int mk = 1; mk < 32; mk <<= 1) a += __shfl_xor(a, mk);
        if (kl == 0) qs[r] = (a + p.bq[r]) * 0.0625f;   // 1/sqrt(256)
      }
      __syncthreads();
      // energies over 196 keys
      for (int pp = 0; pp < 13; ++pp) {
        const int s = pp * 16 + w * 2 + rh;
        float a = 0.f;
        if (s < NS) {
          const float* kr = p.keys + ((size_t)b * NS + s) * NK + kl * 4;
#pragma unroll
          for (int i = 0; i < 2; ++i) {
            const float4 k4 = *(const float4*)(kr + i * 128);
            const float4 q4 = *(const float4*)(qs + i * 128 + kl * 4);
            a += k4.x * q4.x + k4.y * q4.y + k4.z * q4.z + k4.w * q4.w;
          }
        }
#pragma unroll
        for (int mk = 1; mk < 32; mk <<= 1) a += __shfl_xor(a, mk);
        if (kl == 0 && s < NS) smx[s] = a;
      }
      __syncthreads();
      float e = -INFINITY;
      if (t < 256) { e = (t < NS) ? smx[t] : -INFINITY; red[t] = e; }
      __syncthreads();
      for (int off = 128; off; off >>= 1) {
        if (t < off) red[t] = fmaxf(red[t], red[t + off]);
        __syncthreads();
      }
      const float mx = red[0];
      __syncthreads();
      float a = 0.f;
      if (t < 256) { a = (t < NS) ? expf(e - mx) : 0.f; red[t] = a; }
      __syncthreads();
      for (int off = 128; off; off >>= 1) {
        if (t < off) red[t] += red[t + off];
        __syncthreads();
      }
      const float inv = 1.0f / red[0];
      if (t < 256) smx[t] = a * inv;
      __syncthreads();
      if (t < 256) {
        const float* vb = p.values + (size_t)b * NS * NK + t;
        float c0_ = 0.f, c1_ = 0.f, c2_ = 0.f, c3_ = 0.f;
        for (int s = 0; s < NS; s += 4) {
          c0_ += smx[s + 0] * vb[(size_t)(s + 0) * NK];
          c1_ += smx[s + 1] * vb[(size_t)(s + 1) * NK];
          c2_ += smx[s + 2] * vb[(size_t)(s + 2) * NK];
          c3_ += smx[s + 3] * vb[(size_t)(s + 3) * NK];
        }
        astf(&p.ctx[t * 32 + b], (c0_ + c1_) + (c2_ + c3_));
      }
    } else if (bid < NPRED) {
      // pred rows rbase..rbase+47; this phase: k = 0..511 (h1n)
      const int b = lane & 31, kq = lane >> 5;
      const int rbase = bid * 48 + w * 6;
      int rc[6];
#pragma unroll
      for (int r = 0; r < 6; ++r) rc[r] = (rbase + r < NV) ? (rbase + r) : (NV - 1);
#pragma unroll 2
      for (int j = 0; j < 64; ++j) {
        const int k0 = kq * 256 + j * 4;
        float4 x4;
        x4.x = aldf(h1n + (k0 + 0) * 32 + b);
        x4.y = aldf(h1n + (k0 + 1) * 32 + b);
        x4.z = aldf(h1n + (k0 + 2) * 32 + b);
        x4.w = aldf(h1n + (k0 + 3) * 32 + b);
#pragma unroll
        for (int r = 0; r < 6; ++r) {
          const float4 w4 = *(const float4*)(p.Wp + (size_t)rc[r] * 768 + k0);
          acc[r] += w4.x * x4.x + w4.y * x4.y + w4.z * x4.z + w4.w * x4.w;
        }
      }
    }
    gbar(p.bar, bid, ep++, false);

    // ===== P4: pred-ctx part + reduce + coalesced out + argmax =====
    if (bid < NPRED) {
      const int b = lane & 31, kq = lane >> 5;
      const int rbase = bid * 48 + w * 6;
      int rc[6];
#pragma unroll
      for (int r = 0; r < 6; ++r) rc[r] = (rbase + r < NV) ? (rbase + r) : (NV - 1);
#pragma unroll 2
      for (int j = 0; j < 32; ++j) {
        const int kc_ = kq * 128 + j * 4;
        float4 x4;
        x4.x = aldf(p.ctx + (kc_ + 0) * 32 + b);
        x4.y = aldf(p.ctx + (kc_ + 1) * 32 + b);
        x4.z = aldf(p.ctx + (kc_ + 2) * 32 + b);
        x4.w = aldf(p.ctx + (kc_ + 3) * 32 + b);
#pragma unroll
        for (int r = 0; r < 6; ++r) {
          const float4 w4 = *(const float4*)(p.Wp + (size_t)rc[r] * 768 + 512 + kc_);
          acc[r] += w4.x * x4.x + w4.y * x4.y + w4.z * x4.z + w4.w * x4.w;
        }
      }
#pragma unroll
      for (int r = 0; r < 6; ++r) acc[r] += __shfl_xor(acc[r], 32);
      if (kq == 0) {
#pragma unroll
        for (int r = 0; r < 6; ++r)
          arena[(w * 6 + r) * 32 + b] = acc[r];
      }
      __syncthreads();
      if (t < 384) {
        const int b2 = t & 31, rg = t >> 5;   // 12 row-groups of 4
        const int vb = bid * 48 + rg * 4;
        u64 m = 0ull;
        if (vb + 3 < NV) {
          float4 v;
          float* vp = &v.x;
#pragma unroll
          for (int i = 0; i < 4; ++i) {
            const int row = rg * 4 + i;
            vp[i] = arena[row * 32 + b2] + p.bp[vb + i];
          }
          *(float4*)(p.out + ((size_t)b2 * NT + step) * NV + vb) = v;
          m = packmax(v.x, vb + 0);
          const u64 o1 = packmax(v.y, vb + 1); if (o1 > m) m = o1;
          const u64 o2 = packmax(v.z, vb + 2); if (o2 > m) m = o2;
          const u64 o3 = packmax(v.w, vb + 3); if (o3 > m) m = o3;
        }
        cand2[b2][rg] = m;
      }
      __syncthreads();
      if (t < 32) {
        u64 mm = cand2[t][0];
#pragma unroll
        for (int i = 1; i < 12; ++i) { const u64 o = cand2[t][i]; if (o > mm) mm = o; }
        (void)__hip_atomic_fetch_max(&p.amax[(bid & 7) * 32 + t], mm, __ATOMIC_RELAXED, SCOPE);
      }
    }
    gbar(p.bar, bid, ep++, false);
  }
#undef GP
#undef GS
}

// ---------------- host ----------------
extern "C" void kernel_launch(void* const* d_in, const int* in_sizes, int n_in,
                              void* d_out, int out_size, void* d_ws, size_t ws_size,
                              hipStream_t stream) {
  (void)in_sizes; (void)n_in; (void)out_size; (void)ws_size;
  Params prm;
  prm.x    = (const float*)d_in[0];
  prm.emb  = (const float*)d_in[1];
  prm.Wk   = (const float*)d_in[2];
  prm.bk   = (const float*)d_in[3];
  prm.Wv   = (const float*)d_in[4];
  prm.bv   = (const float*)d_in[5];
  prm.Wq   = (const float*)d_in[6];
  prm.bq   = (const float*)d_in[7];
  prm.Wp   = (const float*)d_in[8];
  prm.bp   = (const float*)d_in[9];
  prm.Wih0 = (const float*)d_in[10];
  prm.Whh0 = (const float*)d_in[11];
  prm.bih0 = (const float*)d_in[12];
  prm.bhh0 = (const float*)d_in[13];
  prm.Wih1 = (const float*)d_in[14];
  prm.Whh1 = (const float*)d_in[15];
  prm.bih1 = (const float*)d_in[16];
  prm.bhh1 = (const float*)d_in[17];
  prm.out  = (float*)d_out;

  float* ws = (float*)d_ws;
  prm.keys   = ws;                          // 1,605,632
  prm.values = prm.keys + 1605632;          // 1,605,632
  prm.h0t    = prm.values + 1605632;        // [2][512][32] = 32,768
  prm.h1t    = prm.h0t + 32768;             // 32,768
  prm.c0     = prm.h1t + 32768;             // 16,384 (block-private)
  prm.c1     = prm.c0 + 16384;              // 16,384 (block-private)
  prm.ctx    = prm.c1 + 16384;              // [256][32] = 8,192
  prm.amax   = (u64*)(prm.ctx + 8192);      // 256 u64 = 512 f
  prm.bar    = (unsigned*)(prm.amax + 256); // 1,024 u32

  const int LDS = (10240 + 8192 + 4096) * 4;  // 90,112 B dynamic
  (void)hipFuncSetAttribute((const void*)k_all, hipFuncAttributeMaxDynamicSharedMemorySize, LDS);

  k_zbar<<<4, 256, 0, stream>>>(prm.bar);
  void* args[] = { &prm };
  (void)hipLaunchCooperativeKernel((const void*)k_all, dim3(NBLK), dim3(NTHR), args,
                                   (unsigned)LDS, stream);
}